// Round 1
// baseline (13.558 us; speedup 1.0000x reference)
//
#include <hip/hip_runtime.h>
#include <math.h>

#define T_SIZE 4096   // table entries
#define R_SIZE 4096   // reference features
#define B_SIZE 65536  // batch
#define LOG2E 1.4426950408889634f

__device__ __forceinline__ float fast_exp2(float v) {
#if __has_builtin(__builtin_amdgcn_exp2f)
    return __builtin_amdgcn_exp2f(v);
#else
    return exp2f(v);
#endif
}

// One workgroup = 4 waves = 4 table entries. Stage (p_j, W_j) for all 4096
// refs into LDS (32KB -> 5 blocks/CU), then each wave reduces its entry:
//   g(f) = b_cls + 2^(-2 f^2 log2e) * sum_j W_j * 2^(f * p_j)
// with W_j = w_cls_j * exp(-sy2_j), p_j = 2*log2e*sy_j.
__global__ __launch_bounds__(256) void build_table_kernel(
    const float* __restrict__ ref_feats, const float* __restrict__ w_cls,
    const float* __restrict__ w_out, const float* __restrict__ b_out,
    const float* __restrict__ b_cls, float* __restrict__ table)
{
    __shared__ float2 s_pW[R_SIZE];
    const int tid = threadIdx.x;

    #pragma unroll
    for (int k = 0; k < R_SIZE / 256; ++k) {
        const int j = tid + k * 256;
        const float2 y = ((const float2*)ref_feats)[j];
        const float sy  = y.x + y.y;
        const float sy2 = y.x * y.x + y.y * y.y;
        const float p = 2.0f * LOG2E * sy;
        const float W = w_cls[j] * fast_exp2(-LOG2E * sy2);
        s_pW[j] = make_float2(p, W);
    }
    __syncthreads();

    const int lane = tid & 63;
    const int wid  = tid >> 6;
    const int t    = blockIdx.x * 4 + wid;

    // f-range: f = b_out + w0*h0 + w1*h1, |h_d| < 0.05 strictly.
    const float wo0 = w_out[0], wo1 = w_out[1], bo = b_out[0];
    float span = 0.1f * (fabsf(wo0) + fabsf(wo1));
    span = fmaxf(span, 1e-6f);
    const float lo   = bo - 0.5f * span;
    const float step = span / (float)(T_SIZE - 1);
    const float f    = lo + step * (float)t;

    float a0 = 0.f, a1 = 0.f, a2 = 0.f, a3 = 0.f;
    #pragma unroll 4
    for (int k = 0; k < R_SIZE / 64; k += 4) {
        const float2 v0 = s_pW[(k + 0) * 64 + lane];
        const float2 v1 = s_pW[(k + 1) * 64 + lane];
        const float2 v2 = s_pW[(k + 2) * 64 + lane];
        const float2 v3 = s_pW[(k + 3) * 64 + lane];
        a0 += v0.y * fast_exp2(f * v0.x);
        a1 += v1.y * fast_exp2(f * v1.x);
        a2 += v2.y * fast_exp2(f * v2.x);
        a3 += v3.y * fast_exp2(f * v3.x);
    }
    float s = (a0 + a1) + (a2 + a3);
    #pragma unroll
    for (int off = 32; off; off >>= 1) s += __shfl_down(s, off);

    if (lane == 0) {
        const float scale = fast_exp2(-2.0f * f * f * LOG2E);
        table[t] = b_cls[0] + scale * s;
    }
}

// Per-sample: tiny MLP backbone -> scalar f -> linear interp of g(f).
__global__ __launch_bounds__(256) void fraud_main_kernel(
    const float* __restrict__ x,
    const float* __restrict__ w0, const float* __restrict__ b0,
    const float* __restrict__ wl, const float* __restrict__ bl,
    const float* __restrict__ w_out, const float* __restrict__ b_out,
    const float* __restrict__ table, float* __restrict__ out)
{
    const int i = blockIdx.x * 256 + threadIdx.x;
    const float2 xv = ((const float2*)x)[i];

    float h0 = tanhf(w0[0] * xv.x + w0[1] * xv.y + b0[0]) * 0.1f;
    float h1 = tanhf(w0[2] * xv.x + w0[3] * xv.y + b0[1]) * 0.1f;
    #pragma unroll
    for (int l = 0; l < 3; ++l) {
        const float* W  = wl + 4 * l;
        const float* Bv = bl + 2 * l;
        const float t0 = tanhf(W[0] * h0 + W[1] * h1 + Bv[0]) * 0.05f;
        const float t1 = tanhf(W[2] * h0 + W[3] * h1 + Bv[1]) * 0.05f;
        h0 = t0; h1 = t1;
    }
    const float wo0 = w_out[0], wo1 = w_out[1], bo = b_out[0];
    const float f = wo0 * h0 + wo1 * h1 + bo;

    float span = 0.1f * (fabsf(wo0) + fabsf(wo1));
    span = fmaxf(span, 1e-6f);
    const float lo = bo - 0.5f * span;
    const float inv_step = (float)(T_SIZE - 1) / span;

    float u = (f - lo) * inv_step;
    u = fminf(fmaxf(u, 0.0f), (float)(T_SIZE - 1));
    int i0 = (int)u;
    i0 = min(i0, T_SIZE - 2);
    const float fr = u - (float)i0;
    const float g0 = table[i0];
    const float g1 = table[i0 + 1];
    out[i] = g0 + fr * (g1 - g0);
}

extern "C" void kernel_launch(void* const* d_in, const int* in_sizes, int n_in,
                              void* d_out, int out_size, void* d_ws, size_t ws_size,
                              hipStream_t stream) {
    const float* x      = (const float*)d_in[0];
    const float* w0     = (const float*)d_in[1];
    const float* b0     = (const float*)d_in[2];
    const float* wl     = (const float*)d_in[3];
    const float* bl     = (const float*)d_in[4];
    const float* w_out  = (const float*)d_in[5];
    const float* b_out  = (const float*)d_in[6];
    const float* ref    = (const float*)d_in[7];
    const float* w_cls  = (const float*)d_in[8];
    const float* b_cls  = (const float*)d_in[9];
    float* out   = (float*)d_out;
    float* table = (float*)d_ws;  // 4096 floats = 16KB scratch

    build_table_kernel<<<T_SIZE / 4, 256, 0, stream>>>(ref, w_cls, w_out, b_out, b_cls, table);
    fraud_main_kernel<<<B_SIZE / 256, 256, 0, stream>>>(x, w0, b0, wl, bl, w_out, b_out, table, out);
}

// Round 2
// 12.213 us; speedup vs baseline: 1.1101x; 1.1101x over previous
//
#include <hip/hip_runtime.h>
#include <math.h>

#define T_SIZE 512    // table entries (err ~ 6e-7 << 1.8e-3 threshold)
#define R_SIZE 4096   // reference features
#define B_SIZE 65536  // batch
#define LOG2E 1.4426950408889634f

__device__ __forceinline__ float fast_exp2(float v) {
#if __has_builtin(__builtin_amdgcn_exp2f)
    return __builtin_amdgcn_exp2f(v);
#else
    return exp2f(v);
#endif
}

// One workgroup = 4 waves = 4 table entries. Stage (p_j, W_j) for all 4096
// refs into LDS (32KB), then each wave reduces its entry:
//   g(f) = b_cls + 2^(-2 f^2 log2e) * sum_j W_j * 2^(f * p_j)
// with W_j = w_cls_j * exp(-sy2_j), p_j = 2*log2e*sy_j.
__global__ __launch_bounds__(256) void build_table_kernel(
    const float* __restrict__ ref_feats, const float* __restrict__ w_cls,
    const float* __restrict__ w_out, const float* __restrict__ b_out,
    const float* __restrict__ b_cls, float* __restrict__ table)
{
    __shared__ float2 s_pW[R_SIZE];
    const int tid = threadIdx.x;

    #pragma unroll
    for (int k = 0; k < R_SIZE / 256; ++k) {
        const int j = tid + k * 256;
        const float2 y = ((const float2*)ref_feats)[j];
        const float sy  = y.x + y.y;
        const float sy2 = y.x * y.x + y.y * y.y;
        const float p = 2.0f * LOG2E * sy;
        const float W = w_cls[j] * fast_exp2(-LOG2E * sy2);
        s_pW[j] = make_float2(p, W);
    }
    __syncthreads();

    const int lane = tid & 63;
    const int wid  = tid >> 6;
    const int t    = blockIdx.x * 4 + wid;

    // f-range: f = b_out + w0*h0 + w1*h1, |h_d| < 0.05 strictly.
    const float wo0 = w_out[0], wo1 = w_out[1], bo = b_out[0];
    float span = 0.1f * (fabsf(wo0) + fabsf(wo1));
    span = fmaxf(span, 1e-6f);
    const float lo   = bo - 0.5f * span;
    const float step = span / (float)(T_SIZE - 1);
    const float f    = lo + step * (float)t;

    float a0 = 0.f, a1 = 0.f, a2 = 0.f, a3 = 0.f;
    #pragma unroll 4
    for (int k = 0; k < R_SIZE / 64; k += 4) {
        const float2 v0 = s_pW[(k + 0) * 64 + lane];
        const float2 v1 = s_pW[(k + 1) * 64 + lane];
        const float2 v2 = s_pW[(k + 2) * 64 + lane];
        const float2 v3 = s_pW[(k + 3) * 64 + lane];
        a0 += v0.y * fast_exp2(f * v0.x);
        a1 += v1.y * fast_exp2(f * v1.x);
        a2 += v2.y * fast_exp2(f * v2.x);
        a3 += v3.y * fast_exp2(f * v3.x);
    }
    float s = (a0 + a1) + (a2 + a3);
    #pragma unroll
    for (int off = 32; off; off >>= 1) s += __shfl_down(s, off);

    if (lane == 0) {
        const float scale = fast_exp2(-2.0f * f * f * LOG2E);
        table[t] = b_cls[0] + scale * s;
    }
}

// Per-sample: tiny MLP backbone -> scalar f -> LDS-staged table lerp of g(f).
__global__ __launch_bounds__(256) void fraud_main_kernel(
    const float* __restrict__ x,
    const float* __restrict__ w0, const float* __restrict__ b0,
    const float* __restrict__ wl, const float* __restrict__ bl,
    const float* __restrict__ w_out, const float* __restrict__ b_out,
    const float* __restrict__ table, float* __restrict__ out)
{
    __shared__ float s_tab[T_SIZE];
    const int tid = threadIdx.x;
    const int i = blockIdx.x * 256 + tid;

    // issue x load early; stage table into LDS meanwhile
    const float2 xv = ((const float2*)x)[i];
    s_tab[tid]       = table[tid];
    s_tab[tid + 256] = table[tid + 256];
    __syncthreads();

    float h0 = tanhf(w0[0] * xv.x + w0[1] * xv.y + b0[0]) * 0.1f;
    float h1 = tanhf(w0[2] * xv.x + w0[3] * xv.y + b0[1]) * 0.1f;
    #pragma unroll
    for (int l = 0; l < 3; ++l) {
        const float* W  = wl + 4 * l;
        const float* Bv = bl + 2 * l;
        const float t0 = tanhf(W[0] * h0 + W[1] * h1 + Bv[0]) * 0.05f;
        const float t1 = tanhf(W[2] * h0 + W[3] * h1 + Bv[1]) * 0.05f;
        h0 = t0; h1 = t1;
    }
    const float wo0 = w_out[0], wo1 = w_out[1], bo = b_out[0];
    const float f = wo0 * h0 + wo1 * h1 + bo;

    float span = 0.1f * (fabsf(wo0) + fabsf(wo1));
    span = fmaxf(span, 1e-6f);
    const float lo = bo - 0.5f * span;
    const float inv_step = (float)(T_SIZE - 1) / span;

    float u = (f - lo) * inv_step;
    u = fminf(fmaxf(u, 0.0f), (float)(T_SIZE - 1));
    int i0 = (int)u;
    i0 = min(i0, T_SIZE - 2);
    const float fr = u - (float)i0;
    const float g0 = s_tab[i0];
    const float g1 = s_tab[i0 + 1];
    out[i] = g0 + fr * (g1 - g0);
}

extern "C" void kernel_launch(void* const* d_in, const int* in_sizes, int n_in,
                              void* d_out, int out_size, void* d_ws, size_t ws_size,
                              hipStream_t stream) {
    const float* x      = (const float*)d_in[0];
    const float* w0     = (const float*)d_in[1];
    const float* b0     = (const float*)d_in[2];
    const float* wl     = (const float*)d_in[3];
    const float* bl     = (const float*)d_in[4];
    const float* w_out  = (const float*)d_in[5];
    const float* b_out  = (const float*)d_in[6];
    const float* ref    = (const float*)d_in[7];
    const float* w_cls  = (const float*)d_in[8];
    const float* b_cls  = (const float*)d_in[9];
    float* out   = (float*)d_out;
    float* table = (float*)d_ws;  // 512 floats = 2KB scratch

    build_table_kernel<<<T_SIZE / 4, 256, 0, stream>>>(ref, w_cls, w_out, b_out, b_cls, table);
    fraud_main_kernel<<<B_SIZE / 256, 256, 0, stream>>>(x, w0, b0, wl, bl, w_out, b_out, table, out);
}

// Round 4
// 9.716 us; speedup vs baseline: 1.3954x; 1.2571x over previous
//
#include <hip/hip_runtime.h>
#include <math.h>

#define R_SIZE 4096
#define B_SIZE 65536
#define NN 8                      // Chebyshev nodes -> degree-7 interpolant
#define LOG2E 1.4426950408889634f

__device__ __forceinline__ float fast_exp2(float v) {
#if __has_builtin(__builtin_amdgcn_exp2f)
    return __builtin_amdgcn_exp2f(v);
#else
    return exp2f(v);
#endif
}

// Single fused kernel. Each WG (256 thr = 1 sample/thread) redundantly:
//  1) accumulates gt(f_k) = sum_j w_cls_j * 2^(f_k*p_j - q_j) at the 8
//     Chebyshev nodes f_k of the provable f-range (p=2*log2e*sy, q=log2e*sy2),
//  2) butterfly+LDS reduces the 8 sums,
//  3) projects to Chebyshev coefficients via a constant 8x8 DCT,
//  4) runs the tiny tanh MLP to get f_i, evaluates gt via Clenshaw, and
//     applies the Gaussian prefactor:  logits = 2^(-2 f^2 log2e) * gt(f) + b_cls.
//     (R3 bug was omitting that prefactor.)
// Interp error <= hs^8 max|gt^(8)| / (2^7 8!) ~ 1e-8  << 1.8e-3.
__global__ __launch_bounds__(256) void fraud_fused_kernel(
    const float* __restrict__ x,
    const float* __restrict__ w0, const float* __restrict__ b0,
    const float* __restrict__ wl, const float* __restrict__ bl,
    const float* __restrict__ w_out, const float* __restrict__ b_out,
    const float* __restrict__ ref_feats, const float* __restrict__ w_cls,
    const float* __restrict__ b_cls,
    float* __restrict__ out)
{
    const int tid  = threadIdx.x;
    const int lane = tid & 63;
    const int wid  = tid >> 6;
    const int i    = blockIdx.x * 256 + tid;

    const float2 xv = ((const float2*)x)[i];

    // f = b_out + w_out.h, |h_d| < 0.05 strictly -> f in bo +- hs
    const float wo0 = w_out[0], wo1 = w_out[1], bo = b_out[0];
    float hs = 0.05f * (fabsf(wo0) + fabsf(wo1));
    hs = fmaxf(hs, 5e-7f);

    // Chebyshev nodes u_k = cos(pi(k+1/2)/8)
    const float U[NN] = { 0.980785280f,  0.831469612f,  0.555570233f,  0.195090322f,
                         -0.195090322f, -0.555570233f, -0.831469612f, -0.980785281f};
    float fk[NN];
    #pragma unroll
    for (int k = 0; k < NN; ++k) fk[k] = bo + hs * U[k];

    // node sums over this thread's 16 refs (8 float4 pairs, stride-256 coalesced)
    float acc[NN] = {0.f,0.f,0.f,0.f,0.f,0.f,0.f,0.f};
    #pragma unroll
    for (int m = 0; m < 8; ++m) {
        const int j2 = tid + m * 256;                        // pair index
        const float4 y = ((const float4*)ref_feats)[j2];     // refs 2*j2, 2*j2+1
        const float2 w = ((const float2*)w_cls)[j2];
        const float p0 = 2.0f * LOG2E * (y.x + y.y);
        const float q0 = LOG2E * (y.x * y.x + y.y * y.y);
        const float p1 = 2.0f * LOG2E * (y.z + y.w);
        const float q1 = LOG2E * (y.z * y.z + y.w * y.w);
        #pragma unroll
        for (int k = 0; k < NN; ++k) {
            acc[k] += w.x * fast_exp2(fk[k] * p0 - q0);
            acc[k] += w.y * fast_exp2(fk[k] * p1 - q1);
        }
    }

    // wave64 butterfly reduce each node sum
    #pragma unroll
    for (int k = 0; k < NN; ++k) {
        float v = acc[k];
        #pragma unroll
        for (int off = 32; off; off >>= 1) v += __shfl_xor(v, off);
        acc[k] = v;
    }

    __shared__ float s_red[4][NN];
    if (lane == 0) {
        #pragma unroll
        for (int k = 0; k < NN; ++k) s_red[wid][k] = acc[k];
    }
    __syncthreads();

    float g[NN];
    #pragma unroll
    for (int k = 0; k < NN; ++k)
        g[k] = (s_red[0][k] + s_red[1][k]) + (s_red[2][k] + s_red[3][k]);

    // DCT-II projection -> Chebyshev coefficients (constant 8x8, n=1..7)
    const float M[7][NN] = {
      { 0.980785280f,  0.831469612f,  0.555570233f,  0.195090322f, -0.195090322f, -0.555570233f, -0.831469612f, -0.980785281f},
      { 0.923879533f,  0.382683432f, -0.382683432f, -0.923879533f, -0.923879533f, -0.382683432f,  0.382683432f,  0.923879533f},
      { 0.831469612f, -0.195090322f, -0.980785281f, -0.555570233f,  0.555570233f,  0.980785281f,  0.195090322f, -0.831469612f},
      { 0.707106781f, -0.707106781f, -0.707106781f,  0.707106781f,  0.707106781f, -0.707106781f, -0.707106781f,  0.707106781f},
      { 0.555570233f, -0.980785281f,  0.195090322f,  0.831469612f, -0.831469612f, -0.195090322f,  0.980785281f, -0.555570233f},
      { 0.382683432f, -0.923879533f,  0.923879533f, -0.382683432f, -0.382683432f,  0.923879533f, -0.923879533f,  0.382683432f},
      { 0.195090322f, -0.555570233f,  0.831469612f, -0.980785281f,  0.980785281f, -0.831469612f,  0.555570233f, -0.195090322f}};
    float c[NN];
    c[0] = 0.125f * (((g[0] + g[1]) + (g[2] + g[3])) + ((g[4] + g[5]) + (g[6] + g[7])));
    #pragma unroll
    for (int n = 1; n < NN; ++n) {
        float s = 0.f;
        #pragma unroll
        for (int k = 0; k < NN; ++k) s += M[n - 1][k] * g[k];
        c[n] = 0.25f * s;
    }

    // tiny MLP backbone -> scalar f
    float h0 = tanhf(w0[0] * xv.x + w0[1] * xv.y + b0[0]) * 0.1f;
    float h1 = tanhf(w0[2] * xv.x + w0[3] * xv.y + b0[1]) * 0.1f;
    #pragma unroll
    for (int l = 0; l < 3; ++l) {
        const float* W  = wl + 4 * l;
        const float* Bv = bl + 2 * l;
        const float t0 = tanhf(W[0] * h0 + W[1] * h1 + Bv[0]) * 0.05f;
        const float t1 = tanhf(W[2] * h0 + W[3] * h1 + Bv[1]) * 0.05f;
        h0 = t0; h1 = t1;
    }
    const float f = wo0 * h0 + wo1 * h1 + bo;

    // Clenshaw evaluation at u = (f - bo)/hs  (|u| <= 1 by construction)
    const float u  = (f - bo) / hs;
    const float tu = 2.0f * u;
    float b1 = 0.f, b2 = 0.f;
    #pragma unroll
    for (int n = 7; n >= 1; --n) {
        const float t = tu * b1 - b2 + c[n];
        b2 = b1; b1 = t;
    }
    const float gt = u * b1 - b2 + c[0];

    // Gaussian prefactor (this was the R3 bug)
    const float scale = fast_exp2(-2.0f * f * f * LOG2E);
    out[i] = scale * gt + b_cls[0];
}

extern "C" void kernel_launch(void* const* d_in, const int* in_sizes, int n_in,
                              void* d_out, int out_size, void* d_ws, size_t ws_size,
                              hipStream_t stream) {
    const float* x      = (const float*)d_in[0];
    const float* w0     = (const float*)d_in[1];
    const float* b0     = (const float*)d_in[2];
    const float* wl     = (const float*)d_in[3];
    const float* bl     = (const float*)d_in[4];
    const float* w_out  = (const float*)d_in[5];
    const float* b_out  = (const float*)d_in[6];
    const float* ref    = (const float*)d_in[7];
    const float* w_cls  = (const float*)d_in[8];
    const float* b_cls  = (const float*)d_in[9];
    float* out = (float*)d_out;

    fraud_fused_kernel<<<B_SIZE / 256, 256, 0, stream>>>(
        x, w0, b0, wl, bl, w_out, b_out, ref, w_cls, b_cls, out);
}